// Round 16
// baseline (748.633 us; speedup 1.0000x reference)
//
#include <hip/hip_runtime.h>
#include <hip/hip_bf16.h>

typedef __bf16 bf16x8 __attribute__((ext_vector_type(8)));
typedef __bf16 bf16x4 __attribute__((ext_vector_type(4)));
typedef float  f32x4  __attribute__((ext_vector_type(4)));

typedef __attribute__((address_space(3))) void lds_vp;
typedef const __attribute__((address_space(1))) void gbl_vp;

// ---------------- cast fp32 -> bf16, 8 elems/thread ----------------
__global__ void cast_f32_bf16(const float* __restrict__ src, __bf16* __restrict__ dst, int n8) {
    int i = blockIdx.x * 256 + threadIdx.x;
    if (i >= n8) return;
    const float4* s = (const float4*)src;
    float4 a = s[2 * i], b = s[2 * i + 1];
    bf16x8 o;
    o[0] = (__bf16)a.x; o[1] = (__bf16)a.y; o[2] = (__bf16)a.z; o[3] = (__bf16)a.w;
    o[4] = (__bf16)b.x; o[5] = (__bf16)b.y; o[6] = (__bf16)b.z; o[7] = (__bf16)b.w;
    ((bf16x8*)dst)[i] = o;
}

// ---------------- 128x128 2-phase GEMM, global_load_lds staging (R14-proven) -----
template <int OUT_BF16>
__global__ __launch_bounds__(256)
void gemm_bt(const __bf16* __restrict__ A, const __bf16* __restrict__ Bm,
             void* __restrict__ Cout, int M, int N, int K) {
    __shared__ __bf16 As[128 * 64];
    __shared__ __bf16 Bs[128 * 64];
    const int tid = threadIdx.x;
    const int lane = tid & 63, wid = tid >> 6;
    const int g = lane >> 4, lq = lane & 15;
    const int wr = wid >> 1, wc = wid & 1;
    const size_t brow = (size_t)blockIdx.y * 128, bcol = (size_t)blockIdx.x * 128;
    f32x4 acc[4][4] = {};
    const int nkt = K >> 6;

    const int srow8 = lane >> 3;
    const int scol  = ((lane & 7) ^ srow8) << 3;

    for (int kt = 0; kt < nkt; ++kt) {
        __syncthreads();
#pragma unroll
        for (int j = 0; j < 4; ++j) {
            const int rb = (j * 4 + wid) * 8;
            const __bf16* sa = A + (brow + rb + srow8) * (size_t)K + (size_t)kt * 64 + scol;
            const __bf16* sb = Bm + (bcol + rb + srow8) * (size_t)K + (size_t)kt * 64 + scol;
            __builtin_amdgcn_global_load_lds((gbl_vp*)sa, (lds_vp*)(As + rb * 64), 16, 0, 0);
            __builtin_amdgcn_global_load_lds((gbl_vp*)sb, (lds_vp*)(Bs + rb * 64), 16, 0, 0);
        }
        asm volatile("s_waitcnt vmcnt(0)" ::: "memory");
        __syncthreads();
#pragma unroll
        for (int ks = 0; ks < 2; ++ks) {
            bf16x8 af[4], bfr[4];
            const int kb = ks * 64 + g * 16;
#pragma unroll
            for (int i = 0; i < 4; ++i) {
                int row = wr * 64 + i * 16 + lq;
                af[i] = *(const bf16x8*)((const char*)As + row * 128 + (kb ^ ((row & 7) << 4)));
            }
#pragma unroll
            for (int j = 0; j < 4; ++j) {
                int row = wc * 64 + j * 16 + lq;
                bfr[j] = *(const bf16x8*)((const char*)Bs + row * 128 + (kb ^ ((row & 7) << 4)));
            }
#pragma unroll
            for (int i = 0; i < 4; ++i)
#pragma unroll
                for (int j = 0; j < 4; ++j)
                    acc[i][j] = __builtin_amdgcn_mfma_f32_16x16x32_bf16(af[i], bfr[j], acc[i][j], 0, 0, 0);
        }
    }
#pragma unroll
    for (int i = 0; i < 4; ++i) {
#pragma unroll
        for (int r = 0; r < 4; ++r) {
            size_t row = brow + wr * 64 + i * 16 + g * 4 + r;
#pragma unroll
            for (int j = 0; j < 4; ++j) {
                size_t col = bcol + wc * 64 + j * 16 + lq;
                float v = acc[i][j][r];
                if (OUT_BF16) ((__bf16*)Cout)[row * N + col] = (__bf16)v;
                else          ((float*)Cout)[row * N + col] = v;
            }
        }
    }
}

// ---------------- 256x256 8-phase GEMM (R8-proven; ~137us on gemm2) -------------
__device__ __forceinline__ void stage_half(const __bf16* __restrict__ g, int K, int kt,
                                           __bf16* lds_tile, int h, int w, int l) {
#pragma unroll
    for (int j = 0; j < 2; ++j) {
        const int rih = (j * 8 + w) * 8 + (l >> 3);
        const __bf16* src = g + (size_t)(h * 128 + rih) * K + kt * 64 + (((l & 7) ^ (l >> 3)) << 3);
        __bf16* dst = lds_tile + h * 8192 + (j * 8 + w) * 512;
        __builtin_amdgcn_global_load_lds((gbl_vp*)src, (lds_vp*)dst, 16, 0, 0);
    }
}

__device__ __forceinline__ bf16x8 lds_frag(const __bf16* base, int row, int kb) {
    return *(const bf16x8*)((const char*)base + row * 128 + (kb ^ ((row & 7) << 4)));
}

template <int OUT_BF16>
__global__ __launch_bounds__(512, 2)
void gemm256(const __bf16* __restrict__ A, const __bf16* __restrict__ Bm,
             void* __restrict__ Cout, int M, int N, int K) {
    __shared__ __bf16 As[2][256 * 64];
    __shared__ __bf16 Bs[2][256 * 64];
    const int tid = threadIdx.x;
    const int lane = tid & 63, wid = tid >> 6;
    const int g = lane >> 4, lq = lane & 15;
    const int wm = wid >> 2, wn = wid & 3;
    const size_t brow = (size_t)blockIdx.y * 256, bcol = (size_t)blockIdx.x * 256;
    const __bf16* Ag = A + brow * K;
    const __bf16* Bg = Bm + bcol * K;
    const int nkt = K >> 6, niter = nkt >> 1;

    f32x4 acc[8][4] = {};

    stage_half(Ag, K, 0, &As[0][0], 0, wid, lane);
    stage_half(Bg, K, 0, &Bs[0][0], 0, wid, lane);
    stage_half(Ag, K, 0, &As[0][0], 1, wid, lane);
    stage_half(Bg, K, 0, &Bs[0][0], 1, wid, lane);

    const int arow0 = wm * 128 + lq;
    const int brow0 = wn * 64 + lq;

    for (int it = 0; it < niter; ++it) {
        const int t0 = 2 * it;
#pragma unroll
        for (int hf = 0; hf < 2; ++hf) {
            const __bf16* SA = &As[hf][0];
            const __bf16* SB = &Bs[hf][0];
            __bf16* DA = &As[hf ^ 1][0];
            __bf16* DB = &Bs[hf ^ 1][0];
            const int tstage = t0 + 1 + hf;
            const bool dostage = (tstage < nkt);
            bf16x8 bfr[4][2];

            if (dostage) stage_half(Ag, K, tstage, DA, 0, wid, lane);
            __builtin_amdgcn_sched_barrier(0);
            if (dostage) asm volatile("s_waitcnt vmcnt(2)" ::: "memory");
            else         asm volatile("s_waitcnt vmcnt(0)" ::: "memory");
            __builtin_amdgcn_s_barrier();
            __builtin_amdgcn_sched_barrier(0);
#pragma unroll
            for (int n = 0; n < 4; ++n)
#pragma unroll
                for (int kk = 0; kk < 2; ++kk)
                    bfr[n][kk] = lds_frag(SB, brow0 + n * 16, kk * 64 + g * 16);
            {
                bf16x8 afr[2][2];
#pragma unroll
                for (int mm = 0; mm < 2; ++mm)
#pragma unroll
                    for (int kk = 0; kk < 2; ++kk)
                        afr[mm][kk] = lds_frag(SA, arow0 + mm * 16, kk * 64 + g * 16);
                __builtin_amdgcn_s_setprio(1);
#pragma unroll
                for (int kk = 0; kk < 2; ++kk)
#pragma unroll
                    for (int n = 0; n < 4; ++n)
#pragma unroll
                        for (int mm = 0; mm < 2; ++mm)
                            acc[mm][n] = __builtin_amdgcn_mfma_f32_16x16x32_bf16(afr[mm][kk], bfr[n][kk], acc[mm][n], 0, 0, 0);
                __builtin_amdgcn_s_setprio(0);
            }
            __builtin_amdgcn_sched_barrier(0);
            __builtin_amdgcn_s_barrier();
            __builtin_amdgcn_sched_barrier(0);

#pragma unroll
            for (int q = 1; q < 4; ++q) {
                bf16x8 afr[2][2];
#pragma unroll
                for (int mm = 0; mm < 2; ++mm)
#pragma unroll
                    for (int kk = 0; kk < 2; ++kk)
                        afr[mm][kk] = lds_frag(SA, arow0 + (q * 2 + mm) * 16, kk * 64 + g * 16);
                if (dostage) {
                    if (q == 1)      stage_half(Bg, K, tstage, DB, 0, wid, lane);
                    else if (q == 2) stage_half(Ag, K, tstage, DA, 1, wid, lane);
                    else             stage_half(Bg, K, tstage, DB, 1, wid, lane);
                }
                __builtin_amdgcn_sched_barrier(0);
                __builtin_amdgcn_s_barrier();
                __builtin_amdgcn_sched_barrier(0);
                __builtin_amdgcn_s_setprio(1);
#pragma unroll
                for (int kk = 0; kk < 2; ++kk)
#pragma unroll
                    for (int n = 0; n < 4; ++n)
#pragma unroll
                        for (int mm = 0; mm < 2; ++mm)
                            acc[q * 2 + mm][n] = __builtin_amdgcn_mfma_f32_16x16x32_bf16(afr[mm][kk], bfr[n][kk], acc[q * 2 + mm][n], 0, 0, 0);
                __builtin_amdgcn_s_setprio(0);
                __builtin_amdgcn_sched_barrier(0);
                __builtin_amdgcn_s_barrier();
                __builtin_amdgcn_sched_barrier(0);
            }
        }
    }

#pragma unroll
    for (int m = 0; m < 8; ++m) {
#pragma unroll
        for (int r = 0; r < 4; ++r) {
            size_t row = brow + wm * 128 + m * 16 + g * 4 + r;
#pragma unroll
            for (int n = 0; n < 4; ++n) {
                size_t col = bcol + wn * 64 + n * 16 + lq;
                float v = acc[m][n][r];
                if (OUT_BF16) ((__bf16*)Cout)[row * N + col] = (__bf16)v;
                else          ((float*)Cout)[row * N + col] = v;
            }
        }
    }
}

// ---------------- V transpose: qkv V-part -> vt[(b*8+kh)*128+d][t] ----------------
__global__ __launch_bounds__(256)
void transpose_v(const __bf16* __restrict__ qkv, __bf16* __restrict__ vt) {
    constexpr int S = 2048, QKVN = 6144;
    __shared__ __bf16 tile[64][72];
    const int tt = blockIdx.x;
    const int yz = blockIdx.y;
    const int dh = yz & 1, bkh = yz >> 1;
    const int b = bkh >> 3, kh = bkh & 7;
    const int tid = threadIdx.x;
#pragma unroll
    for (int i = 0; i < 2; ++i) {
        int flat = i * 2048 + tid * 8;
        int r = flat >> 6, c0 = flat & 63;
        const __bf16* src = qkv + ((size_t)b * S + tt * 64 + r) * QKVN + 5120 + kh * 128 + dh * 64 + c0;
        *(bf16x8*)&tile[r][c0] = *(const bf16x8*)src;
    }
    __syncthreads();
#pragma unroll
    for (int i = 0; i < 2; ++i) {
        int flat = i * 2048 + tid * 8;
        int d = flat >> 6, t0 = flat & 63;
        bf16x8 pk;
#pragma unroll
        for (int e = 0; e < 8; ++e) pk[e] = tile[t0 + e][d];
        __bf16* dst = vt + ((size_t)(b * 8 + kh) * 128 + dh * 64 + d) * S + tt * 64 + t0;
        *(bf16x8*)dst = pk;
    }
}

// ---------------- flash attention v10: 8 waves, pairing-robust balance ---------
// R15 null diagnosed: co-resident pairs on a CU are consecutive-within-XCD
// (j, j^1), which share jq -> same qt2 under BOTH old maps -> worst CU 64 units.
// New decode complements qt2 across bit0 AND bit5 of j:
//   s=(j^(j>>5))&1; v=(j>>1)&3; qt2 = s ? v : 7-v; b=(j>>3)&1;
//   g4=((j>>4)&1)|((j&1)<<1)   (bijective; pair sum = 36 units under (j,j^1)
//   AND (j,j^32) pairings; pairs share (kh,b) -> same K/V stream in L2).
__global__ __launch_bounds__(512, 2)
void attn_kernel(const __bf16* __restrict__ qkv, const __bf16* __restrict__ vt,
                 __bf16* __restrict__ outb) {
    constexpr int S = 2048, D = 128, QKVN = 6144;
    const int p = blockIdx.x;                // 512 blocks
    const int kh = p & 7;                    // XCD
    const int j = p >> 3;                    // 0..63
    const int sb2 = (j ^ (j >> 5)) & 1;
    const int v2  = (j >> 1) & 3;
    const int qt2 = sb2 ? v2 : 7 - v2;       // pairing-robust balanced map
    const int b   = (j >> 3) & 1;
    const int g4  = ((j >> 4) & 1) | ((j & 1) << 1);
    const int h  = kh * 4 + g4;
    const int tid = threadIdx.x, lane = tid & 63, w = tid >> 6;   // w: 0..7
    const int g = lane >> 4, lq = lane & 15;

    __shared__ __bf16 Ks[64 * 128];          // [t][d], rows 256B, XOR (row&15)<<4
    __shared__ __bf16 Vs[128 * 64];          // [d][t], rows 128B, XOR (d&7)<<4
    __shared__ char   PsRaw[8][2][16 * 152]; // per-wave, per-frag P rows, stride 152B

    const int wqmin = qt2 * 256 + w * 32;
    const int qg0 = wqmin + lq;
    const int qg1 = qg0 + 16;

    const __bf16* qrow = qkv + ((size_t)(b * S) + wqmin + lq) * QKVN + h * D;
    bf16x8 qf0[4], qf1[4];
#pragma unroll
    for (int ks = 0; ks < 4; ++ks) {
        qf0[ks] = *(const bf16x8*)(qrow + ks * 32 + g * 8);
        qf1[ks] = *(const bf16x8*)(qrow + (size_t)16 * QKVN + ks * 32 + g * 8);
    }

    const char* kbase = (const char*)qkv + ((size_t)(b * S) * QKVN + 4096 + kh * D) * 2;
    const char* vbase = (const char*)vt + ((size_t)(b * 8 + kh) * D * S) * 2;

    f32x4 acc0[8] = {}, acc1[8] = {};
    float m0 = -1e30f, l0 = 0.f, m1 = -1e30f, l1 = 0.f;
    const float scale2 = 0.12753102494f;     // (1/sqrt(128)) * log2(e)

    const int krow0 = tid >> 4;              // 0..31
    const int kcolb = (tid & 15) * 16;
    const int vrow0 = tid >> 3;              // 0..63
    const int vcolb = (tid & 7) * 16;

    const int ktmax = 4 * qt2 + 3;
    int4 pk[2], pv[2];
#pragma unroll
    for (int is = 0; is < 2; ++is) {
        pk[is] = *(const int4*)(kbase + (size_t)(is * 32 + krow0) * QKVN * 2 + kcolb);
        pv[is] = *(const int4*)(vbase + (size_t)(is * 64 + vrow0) * S * 2 + vcolb);
    }

    char* ps0 = &PsRaw[w][0][0];
    char* ps1 = &PsRaw[w][1][0];

    for (int kt = 0; kt <= ktmax; ++kt) {
        __builtin_amdgcn_s_barrier();        // all waves done reading prev tile
#pragma unroll
        for (int is = 0; is < 2; ++is) {
            int row = is * 32 + krow0;
            *(int4*)((char*)Ks + row * 256 + (kcolb ^ ((row & 15) << 4))) = pk[is];
            int d = is * 64 + vrow0;
            *(int4*)((char*)Vs + d * 128 + (vcolb ^ ((d & 7) << 4))) = pv[is];
        }
        if (kt < ktmax) {                    // prefetch next tile (registers only)
#pragma unroll
            for (int is = 0; is < 2; ++is) {
                pk[is] = *(const int4*)(kbase + (size_t)((kt + 1) * 64 + is * 32 + krow0) * QKVN * 2 + kcolb);
                pv[is] = *(const int4*)(vbase + ((size_t)(is * 64 + vrow0) * S + (kt + 1) * 64) * 2 + vcolb);
            }
        }
        __builtin_amdgcn_sched_barrier(0);
        asm volatile("s_waitcnt lgkmcnt(0)" ::: "memory");
        __builtin_amdgcn_sched_barrier(0);
        __builtin_amdgcn_s_barrier();        // vmcnt stays outstanding
        __builtin_amdgcn_sched_barrier(0);

        if (kt * 64 <= wqmin + 31) {         // wave-level causal skip
            f32x4 sc0[4], sc1[4];
            __builtin_amdgcn_s_setprio(1);
#pragma unroll
            for (int tb = 0; tb < 4; ++tb) {
                f32x4 s0 = {0.f, 0.f, 0.f, 0.f}, s1 = {0.f, 0.f, 0.f, 0.f};
                const int trow = tb * 16 + lq;
                const int rsw = (trow & 15) << 4;
#pragma unroll
                for (int ks = 0; ks < 4; ++ks) {
                    bf16x8 kf = *(const bf16x8*)((const char*)Ks + trow * 256 + ((ks * 64 + g * 16) ^ rsw));
                    s0 = __builtin_amdgcn_mfma_f32_16x16x32_bf16(kf, qf0[ks], s0, 0, 0, 0);
                    s1 = __builtin_amdgcn_mfma_f32_16x16x32_bf16(kf, qf1[ks], s1, 0, 0, 0);
                }
                sc0[tb] = s0; sc1[tb] = s1;
            }
            __builtin_amdgcn_s_setprio(0);

#pragma unroll
            for (int f = 0; f < 2; ++f) {
                f32x4* sc = f ? sc1 : sc0;
                float& m_r = f ? m1 : m0;
                float& l_p = f ? l1 : l0;
                f32x4* acc = f ? acc1 : acc0;
                char* ps = f ? ps1 : ps0;
                const int qg = f ? qg1 : qg0;
                const bool domask = (kt * 64 + 63 > qg - lq);

                float pr[16];
                float rowmax = -1e30f;
#pragma unroll
                for (int tb = 0; tb < 4; ++tb)
#pragma unroll
                    for (int r = 0; r < 4; ++r) {
                        float sv = sc[tb][r] * scale2;
                        if (domask) {
                            int tg = kt * 64 + tb * 16 + g * 4 + r;
                            sv = (tg <= qg) ? sv : -1e30f;
                        }
                        pr[tb * 4 + r] = sv;
                        rowmax = fmaxf(rowmax, sv);
                    }
                rowmax = fmaxf(rowmax, __shfl_xor(rowmax, 16));
                rowmax = fmaxf(rowmax, __shfl_xor(rowmax, 32));
                if (!__all(rowmax - m_r <= 11.0f)) {
                    float m_new = fmaxf(m_r, rowmax);
                    float alpha = exp2f(m_r - m_new);
                    l_p *= alpha;
#pragma unroll
                    for (int r = 0; r < 4; ++r) {
                        float ar = __shfl(alpha, g * 4 + r);
#pragma unroll
                        for (int nb = 0; nb < 8; ++nb) acc[nb][r] *= ar;
                    }
                    m_r = m_new;
                }
                float lsum = 0.f;
#pragma unroll
                for (int i = 0; i < 16; ++i) {
                    float e = exp2f(pr[i] - m_r);
                    pr[i] = e;
                    lsum += e;
                }
                l_p += lsum;
#pragma unroll
                for (int tb = 0; tb < 4; ++tb) {
                    bf16x4 pkv;
#pragma unroll
                    for (int r = 0; r < 4; ++r) pkv[r] = (__bf16)pr[tb * 4 + r];
                    *(bf16x4*)(ps + lq * 152 + tb * 32 + g * 8) = pkv;
                }
            }

            __builtin_amdgcn_s_setprio(1);
#pragma unroll
            for (int ks = 0; ks < 2; ++ks) {
                bf16x8 pa0 = *(const bf16x8*)(ps0 + lq * 152 + ks * 64 + g * 16);
                bf16x8 pa1 = *(const bf16x8*)(ps1 + lq * 152 + ks * 64 + g * 16);
#pragma unroll
                for (int nb = 0; nb < 8; ++nb) {
                    int d = nb * 16 + lq;
                    bf16x8 vf = *(const bf16x8*)((const char*)Vs + d * 128 + ((ks * 64 + g * 16) ^ ((d & 7) << 4)));
                    acc0[nb] = __builtin_amdgcn_mfma_f32_16x16x32_bf16(pa0, vf, acc0[nb], 0, 0, 0);
                    acc1[nb] = __builtin_amdgcn_mfma_f32_16x16x32_bf16(pa1, vf, acc1[nb], 0, 0, 0);
                }
            }
            __builtin_amdgcn_s_setprio(0);
        }
        __builtin_amdgcn_sched_barrier(0);
    }

    l0 += __shfl_xor(l0, 16); l0 += __shfl_xor(l0, 32);
    l1 += __shfl_xor(l1, 16); l1 += __shfl_xor(l1, 32);
    float rl0 = 1.f / l0, rl1 = 1.f / l1;
#pragma unroll
    for (int r = 0; r < 4; ++r) {
        float rr0 = __shfl(rl0, g * 4 + r);
        float rr1 = __shfl(rl1, g * 4 + r);
        size_t row0 = (size_t)(b * S) + wqmin + g * 4 + r;
        __bf16* orow0 = outb + row0 * 4096 + h * D;
        __bf16* orow1 = orow0 + (size_t)16 * 4096;
#pragma unroll
        for (int nb = 0; nb < 8; ++nb) {
            orow0[nb * 16 + lq] = (__bf16)(acc0[nb][r] * rr0);
            orow1[nb * 16 + lq] = (__bf16)(acc1[nb][r] * rr1);
        }
    }
}

// ---------------- launch ----------------
extern "C" void kernel_launch(void* const* d_in, const int* in_sizes, int n_in,
                              void* d_out, int out_size, void* d_ws, size_t ws_size,
                              hipStream_t stream) {
    (void)in_sizes; (void)n_in; (void)out_size; (void)ws_size;
    const float* q       = (const float*)d_in[0];
    const float* w_qkv   = (const float*)d_in[1];
    const float* w_dense = (const float*)d_in[2];
    float* out = (float*)d_out;
    char* ws = (char*)d_ws;

    __bf16* qbf      = (__bf16*)(ws);
    __bf16* wqkvbf   = (__bf16*)(ws + 33554432ULL);
    __bf16* wdensebf = (__bf16*)(ws + 83886080ULL);
    __bf16* qkvbf    = (__bf16*)(ws + 117440512ULL);
    __bf16* vtbf     = (__bf16*)(ws + 167772160ULL);
    __bf16* attnbf   = (__bf16*)(ws + 176160768ULL);

    cast_f32_bf16<<<8192, 256, 0, stream>>>(q, qbf, 2097152);
    cast_f32_bf16<<<12288, 256, 0, stream>>>(w_qkv, wqkvbf, 3145728);
    cast_f32_bf16<<<8192, 256, 0, stream>>>(w_dense, wdensebf, 2097152);

    gemm_bt<1><<<dim3(48, 32), 256, 0, stream>>>(qbf, wqkvbf, (void*)qkvbf, 4096, 6144, 4096);
    transpose_v<<<dim3(32, 32), 256, 0, stream>>>(qkvbf, vtbf);
    attn_kernel<<<512, 512, 0, stream>>>(qkvbf, vtbf, attnbf);
    gemm256<0><<<dim3(16, 16), 512, 0, stream>>>(attnbf, wdensebf, (void*)out, 4096, 4096, 4096);
}

// Round 17
// 649.880 us; speedup vs baseline: 1.1520x; 1.1520x over previous
//
#include <hip/hip_runtime.h>
#include <hip/hip_bf16.h>

typedef __bf16 bf16x8 __attribute__((ext_vector_type(8)));
typedef __bf16 bf16x4 __attribute__((ext_vector_type(4)));
typedef float  f32x4  __attribute__((ext_vector_type(4)));

typedef __attribute__((address_space(3))) void lds_vp;
typedef const __attribute__((address_space(1))) void gbl_vp;

// ---------------- cast fp32 -> bf16, 8 elems/thread ----------------
__global__ void cast_f32_bf16(const float* __restrict__ src, __bf16* __restrict__ dst, int n8) {
    int i = blockIdx.x * 256 + threadIdx.x;
    if (i >= n8) return;
    const float4* s = (const float4*)src;
    float4 a = s[2 * i], b = s[2 * i + 1];
    bf16x8 o;
    o[0] = (__bf16)a.x; o[1] = (__bf16)a.y; o[2] = (__bf16)a.z; o[3] = (__bf16)a.w;
    o[4] = (__bf16)b.x; o[5] = (__bf16)b.y; o[6] = (__bf16)b.z; o[7] = (__bf16)b.w;
    ((bf16x8*)dst)[i] = o;
}

// ---------------- 128x128 2-phase GEMM, global_load_lds staging (R14-proven) -----
template <int OUT_BF16>
__global__ __launch_bounds__(256)
void gemm_bt(const __bf16* __restrict__ A, const __bf16* __restrict__ Bm,
             void* __restrict__ Cout, int M, int N, int K) {
    __shared__ __bf16 As[128 * 64];
    __shared__ __bf16 Bs[128 * 64];
    const int tid = threadIdx.x;
    const int lane = tid & 63, wid = tid >> 6;
    const int g = lane >> 4, lq = lane & 15;
    const int wr = wid >> 1, wc = wid & 1;
    const size_t brow = (size_t)blockIdx.y * 128, bcol = (size_t)blockIdx.x * 128;
    f32x4 acc[4][4] = {};
    const int nkt = K >> 6;

    const int srow8 = lane >> 3;
    const int scol  = ((lane & 7) ^ srow8) << 3;

    for (int kt = 0; kt < nkt; ++kt) {
        __syncthreads();
#pragma unroll
        for (int j = 0; j < 4; ++j) {
            const int rb = (j * 4 + wid) * 8;
            const __bf16* sa = A + (brow + rb + srow8) * (size_t)K + (size_t)kt * 64 + scol;
            const __bf16* sb = Bm + (bcol + rb + srow8) * (size_t)K + (size_t)kt * 64 + scol;
            __builtin_amdgcn_global_load_lds((gbl_vp*)sa, (lds_vp*)(As + rb * 64), 16, 0, 0);
            __builtin_amdgcn_global_load_lds((gbl_vp*)sb, (lds_vp*)(Bs + rb * 64), 16, 0, 0);
        }
        asm volatile("s_waitcnt vmcnt(0)" ::: "memory");
        __syncthreads();
#pragma unroll
        for (int ks = 0; ks < 2; ++ks) {
            bf16x8 af[4], bfr[4];
            const int kb = ks * 64 + g * 16;
#pragma unroll
            for (int i = 0; i < 4; ++i) {
                int row = wr * 64 + i * 16 + lq;
                af[i] = *(const bf16x8*)((const char*)As + row * 128 + (kb ^ ((row & 7) << 4)));
            }
#pragma unroll
            for (int j = 0; j < 4; ++j) {
                int row = wc * 64 + j * 16 + lq;
                bfr[j] = *(const bf16x8*)((const char*)Bs + row * 128 + (kb ^ ((row & 7) << 4)));
            }
#pragma unroll
            for (int i = 0; i < 4; ++i)
#pragma unroll
                for (int j = 0; j < 4; ++j)
                    acc[i][j] = __builtin_amdgcn_mfma_f32_16x16x32_bf16(af[i], bfr[j], acc[i][j], 0, 0, 0);
        }
    }
#pragma unroll
    for (int i = 0; i < 4; ++i) {
#pragma unroll
        for (int r = 0; r < 4; ++r) {
            size_t row = brow + wr * 64 + i * 16 + g * 4 + r;
#pragma unroll
            for (int j = 0; j < 4; ++j) {
                size_t col = bcol + wc * 64 + j * 16 + lq;
                float v = acc[i][j][r];
                if (OUT_BF16) ((__bf16*)Cout)[row * N + col] = (__bf16)v;
                else          ((float*)Cout)[row * N + col] = v;
            }
        }
    }
}

// ---------------- 256x256 8-phase GEMM (R8-proven; ~137us on gemm2) -------------
__device__ __forceinline__ void stage_half(const __bf16* __restrict__ g, int K, int kt,
                                           __bf16* lds_tile, int h, int w, int l) {
#pragma unroll
    for (int j = 0; j < 2; ++j) {
        const int rih = (j * 8 + w) * 8 + (l >> 3);
        const __bf16* src = g + (size_t)(h * 128 + rih) * K + kt * 64 + (((l & 7) ^ (l >> 3)) << 3);
        __bf16* dst = lds_tile + h * 8192 + (j * 8 + w) * 512;
        __builtin_amdgcn_global_load_lds((gbl_vp*)src, (lds_vp*)dst, 16, 0, 0);
    }
}

__device__ __forceinline__ bf16x8 lds_frag(const __bf16* base, int row, int kb) {
    return *(const bf16x8*)((const char*)base + row * 128 + (kb ^ ((row & 7) << 4)));
}

template <int OUT_BF16>
__global__ __launch_bounds__(512, 2)
void gemm256(const __bf16* __restrict__ A, const __bf16* __restrict__ Bm,
             void* __restrict__ Cout, int M, int N, int K) {
    __shared__ __bf16 As[2][256 * 64];
    __shared__ __bf16 Bs[2][256 * 64];
    const int tid = threadIdx.x;
    const int lane = tid & 63, wid = tid >> 6;
    const int g = lane >> 4, lq = lane & 15;
    const int wm = wid >> 2, wn = wid & 3;
    const size_t brow = (size_t)blockIdx.y * 256, bcol = (size_t)blockIdx.x * 256;
    const __bf16* Ag = A + brow * K;
    const __bf16* Bg = Bm + bcol * K;
    const int nkt = K >> 6, niter = nkt >> 1;

    f32x4 acc[8][4] = {};

    stage_half(Ag, K, 0, &As[0][0], 0, wid, lane);
    stage_half(Bg, K, 0, &Bs[0][0], 0, wid, lane);
    stage_half(Ag, K, 0, &As[0][0], 1, wid, lane);
    stage_half(Bg, K, 0, &Bs[0][0], 1, wid, lane);

    const int arow0 = wm * 128 + lq;
    const int brow0 = wn * 64 + lq;

    for (int it = 0; it < niter; ++it) {
        const int t0 = 2 * it;
#pragma unroll
        for (int hf = 0; hf < 2; ++hf) {
            const __bf16* SA = &As[hf][0];
            const __bf16* SB = &Bs[hf][0];
            __bf16* DA = &As[hf ^ 1][0];
            __bf16* DB = &Bs[hf ^ 1][0];
            const int tstage = t0 + 1 + hf;
            const bool dostage = (tstage < nkt);
            bf16x8 bfr[4][2];

            if (dostage) stage_half(Ag, K, tstage, DA, 0, wid, lane);
            __builtin_amdgcn_sched_barrier(0);
            if (dostage) asm volatile("s_waitcnt vmcnt(2)" ::: "memory");
            else         asm volatile("s_waitcnt vmcnt(0)" ::: "memory");
            __builtin_amdgcn_s_barrier();
            __builtin_amdgcn_sched_barrier(0);
#pragma unroll
            for (int n = 0; n < 4; ++n)
#pragma unroll
                for (int kk = 0; kk < 2; ++kk)
                    bfr[n][kk] = lds_frag(SB, brow0 + n * 16, kk * 64 + g * 16);
            {
                bf16x8 afr[2][2];
#pragma unroll
                for (int mm = 0; mm < 2; ++mm)
#pragma unroll
                    for (int kk = 0; kk < 2; ++kk)
                        afr[mm][kk] = lds_frag(SA, arow0 + mm * 16, kk * 64 + g * 16);
                __builtin_amdgcn_s_setprio(1);
#pragma unroll
                for (int kk = 0; kk < 2; ++kk)
#pragma unroll
                    for (int n = 0; n < 4; ++n)
#pragma unroll
                        for (int mm = 0; mm < 2; ++mm)
                            acc[mm][n] = __builtin_amdgcn_mfma_f32_16x16x32_bf16(afr[mm][kk], bfr[n][kk], acc[mm][n], 0, 0, 0);
                __builtin_amdgcn_s_setprio(0);
            }
            __builtin_amdgcn_sched_barrier(0);
            __builtin_amdgcn_s_barrier();
            __builtin_amdgcn_sched_barrier(0);

#pragma unroll
            for (int q = 1; q < 4; ++q) {
                bf16x8 afr[2][2];
#pragma unroll
                for (int mm = 0; mm < 2; ++mm)
#pragma unroll
                    for (int kk = 0; kk < 2; ++kk)
                        afr[mm][kk] = lds_frag(SA, arow0 + (q * 2 + mm) * 16, kk * 64 + g * 16);
                if (dostage) {
                    if (q == 1)      stage_half(Bg, K, tstage, DB, 0, wid, lane);
                    else if (q == 2) stage_half(Ag, K, tstage, DA, 1, wid, lane);
                    else             stage_half(Bg, K, tstage, DB, 1, wid, lane);
                }
                __builtin_amdgcn_sched_barrier(0);
                __builtin_amdgcn_s_barrier();
                __builtin_amdgcn_sched_barrier(0);
                __builtin_amdgcn_s_setprio(1);
#pragma unroll
                for (int kk = 0; kk < 2; ++kk)
#pragma unroll
                    for (int n = 0; n < 4; ++n)
#pragma unroll
                        for (int mm = 0; mm < 2; ++mm)
                            acc[q * 2 + mm][n] = __builtin_amdgcn_mfma_f32_16x16x32_bf16(afr[mm][kk], bfr[n][kk], acc[q * 2 + mm][n], 0, 0, 0);
                __builtin_amdgcn_s_setprio(0);
                __builtin_amdgcn_sched_barrier(0);
                __builtin_amdgcn_s_barrier();
                __builtin_amdgcn_sched_barrier(0);
            }
        }
    }

#pragma unroll
    for (int m = 0; m < 8; ++m) {
#pragma unroll
        for (int r = 0; r < 4; ++r) {
            size_t row = brow + wm * 128 + m * 16 + g * 4 + r;
#pragma unroll
            for (int n = 0; n < 4; ++n) {
                size_t col = bcol + wn * 64 + n * 16 + lq;
                float v = acc[m][n][r];
                if (OUT_BF16) ((__bf16*)Cout)[row * N + col] = (__bf16)v;
                else          ((float*)Cout)[row * N + col] = v;
            }
        }
    }
}

// ---------------- V transpose: qkv V-part -> vt[(b*8+kh)*128+d][t] ----------------
__global__ __launch_bounds__(256)
void transpose_v(const __bf16* __restrict__ qkv, __bf16* __restrict__ vt) {
    constexpr int S = 2048, QKVN = 6144;
    __shared__ __bf16 tile[64][72];
    const int tt = blockIdx.x;
    const int yz = blockIdx.y;
    const int dh = yz & 1, bkh = yz >> 1;
    const int b = bkh >> 3, kh = bkh & 7;
    const int tid = threadIdx.x;
#pragma unroll
    for (int i = 0; i < 2; ++i) {
        int flat = i * 2048 + tid * 8;
        int r = flat >> 6, c0 = flat & 63;
        const __bf16* src = qkv + ((size_t)b * S + tt * 64 + r) * QKVN + 5120 + kh * 128 + dh * 64 + c0;
        *(bf16x8*)&tile[r][c0] = *(const bf16x8*)src;
    }
    __syncthreads();
#pragma unroll
    for (int i = 0; i < 2; ++i) {
        int flat = i * 2048 + tid * 8;
        int d = flat >> 6, t0 = flat & 63;
        bf16x8 pk;
#pragma unroll
        for (int e = 0; e < 8; ++e) pk[e] = tile[t0 + e][d];
        __bf16* dst = vt + ((size_t)(b * 8 + kh) * 128 + dh * 64 + d) * S + tt * 64 + t0;
        *(bf16x8*)dst = pk;
    }
}

// ---------------- flash attention v6 (causal, GQA) — R7-proven, FROZEN ----------
// 4 waves x 32 q-rows (2 frags), 128 q-rows/block, 1024 blocks. Raw s_barrier +
// lgkmcnt-only drain (vmcnt rides across barriers), reg-prefetch K/V, swapped
// QK^T, base-2 softmax, defer-max, per-lane partial l. Measured ~182us (R7/R13).
__global__ __launch_bounds__(256, 2)
void attn_kernel(const __bf16* __restrict__ qkv, const __bf16* __restrict__ vt,
                 __bf16* __restrict__ outb) {
    constexpr int S = 2048, D = 128, QKVN = 6144;
    const int p = blockIdx.x;
    const int kh = p & 7;
    const int j = p >> 3;
    const int qt = 15 - (j >> 3);
    const int b  = (j >> 2) & 1;
    const int g4 = j & 3;
    const int h  = kh * 4 + g4;
    const int tid = threadIdx.x, lane = tid & 63, w = tid >> 6;
    const int g = lane >> 4, lq = lane & 15;

    __shared__ __bf16 Ks[64 * 128];
    __shared__ __bf16 Vs[128 * 64];
    __shared__ char   PsRaw[4][2][16 * 152];

    const int wqmin = qt * 128 + w * 32;
    const int qg0 = wqmin + lq;
    const int qg1 = qg0 + 16;

    const __bf16* qrow = qkv + ((size_t)(b * S) + wqmin + lq) * QKVN + h * D;
    bf16x8 qf0[4], qf1[4];
#pragma unroll
    for (int ks = 0; ks < 4; ++ks) {
        qf0[ks] = *(const bf16x8*)(qrow + ks * 32 + g * 8);
        qf1[ks] = *(const bf16x8*)(qrow + (size_t)16 * QKVN + ks * 32 + g * 8);
    }

    const char* kbase = (const char*)qkv + ((size_t)(b * S) * QKVN + 4096 + kh * D) * 2;
    const char* vbase = (const char*)vt + ((size_t)(b * 8 + kh) * D * S) * 2;

    f32x4 acc0[8] = {}, acc1[8] = {};
    float m0 = -1e30f, l0 = 0.f, m1 = -1e30f, l1 = 0.f;
    const float scale2 = 0.12753102494f;

    const int krow0 = tid >> 4;
    const int kcolb = (tid & 15) * 16;
    const int vrow0 = tid >> 3;
    const int vcolb = (tid & 7) * 16;

    const int ktmax = 2 * qt + 1;
    int4 pk[4], pv[4];
#pragma unroll
    for (int is = 0; is < 4; ++is) {
        pk[is] = *(const int4*)(kbase + (size_t)(is * 16 + krow0) * QKVN * 2 + kcolb);
        pv[is] = *(const int4*)(vbase + (size_t)(is * 32 + vrow0) * S * 2 + vcolb);
    }

    char* ps0 = &PsRaw[w][0][0];
    char* ps1 = &PsRaw[w][1][0];

    for (int kt = 0; kt <= ktmax; ++kt) {
        __builtin_amdgcn_s_barrier();
#pragma unroll
        for (int is = 0; is < 4; ++is) {
            int row = is * 16 + krow0;
            *(int4*)((char*)Ks + row * 256 + (kcolb ^ ((row & 15) << 4))) = pk[is];
            int d = is * 32 + vrow0;
            *(int4*)((char*)Vs + d * 128 + (vcolb ^ ((d & 7) << 4))) = pv[is];
        }
        if (kt < ktmax) {
#pragma unroll
            for (int is = 0; is < 4; ++is) {
                pk[is] = *(const int4*)(kbase + (size_t)((kt + 1) * 64 + is * 16 + krow0) * QKVN * 2 + kcolb);
                pv[is] = *(const int4*)(vbase + ((size_t)(is * 32 + vrow0) * S + (kt + 1) * 64) * 2 + vcolb);
            }
        }
        __builtin_amdgcn_sched_barrier(0);
        asm volatile("s_waitcnt lgkmcnt(0)" ::: "memory");
        __builtin_amdgcn_sched_barrier(0);
        __builtin_amdgcn_s_barrier();
        __builtin_amdgcn_sched_barrier(0);

        if (kt * 64 <= wqmin + 31) {
            f32x4 sc0[4], sc1[4];
            __builtin_amdgcn_s_setprio(1);
#pragma unroll
            for (int tb = 0; tb < 4; ++tb) {
                f32x4 s0 = {0.f, 0.f, 0.f, 0.f}, s1 = {0.f, 0.f, 0.f, 0.f};
                const int trow = tb * 16 + lq;
                const int rsw = (trow & 15) << 4;
#pragma unroll
                for (int ks = 0; ks < 4; ++ks) {
                    bf16x8 kf = *(const bf16x8*)((const char*)Ks + trow * 256 + ((ks * 64 + g * 16) ^ rsw));
                    s0 = __builtin_amdgcn_mfma_f32_16x16x32_bf16(kf, qf0[ks], s0, 0, 0, 0);
                    s1 = __builtin_amdgcn_mfma_f32_16x16x32_bf16(kf, qf1[ks], s1, 0, 0, 0);
                }
                sc0[tb] = s0; sc1[tb] = s1;
            }
            __builtin_amdgcn_s_setprio(0);

#pragma unroll
            for (int f = 0; f < 2; ++f) {
                f32x4* sc = f ? sc1 : sc0;
                float& m_r = f ? m1 : m0;
                float& l_p = f ? l1 : l0;
                f32x4* acc = f ? acc1 : acc0;
                char* ps = f ? ps1 : ps0;
                const int qg = f ? qg1 : qg0;
                const bool domask = (kt * 64 + 63 > qg - lq);

                float pr[16];
                float rowmax = -1e30f;
#pragma unroll
                for (int tb = 0; tb < 4; ++tb)
#pragma unroll
                    for (int r = 0; r < 4; ++r) {
                        float sv = sc[tb][r] * scale2;
                        if (domask) {
                            int tg = kt * 64 + tb * 16 + g * 4 + r;
                            sv = (tg <= qg) ? sv : -1e30f;
                        }
                        pr[tb * 4 + r] = sv;
                        rowmax = fmaxf(rowmax, sv);
                    }
                rowmax = fmaxf(rowmax, __shfl_xor(rowmax, 16));
                rowmax = fmaxf(rowmax, __shfl_xor(rowmax, 32));
                if (!__all(rowmax - m_r <= 11.0f)) {
                    float m_new = fmaxf(m_r, rowmax);
                    float alpha = exp2f(m_r - m_new);
                    l_p *= alpha;
#pragma unroll
                    for (int r = 0; r < 4; ++r) {
                        float ar = __shfl(alpha, g * 4 + r);
#pragma unroll
                        for (int nb = 0; nb < 8; ++nb) acc[nb][r] *= ar;
                    }
                    m_r = m_new;
                }
                float lsum = 0.f;
#pragma unroll
                for (int i = 0; i < 16; ++i) {
                    float e = exp2f(pr[i] - m_r);
                    pr[i] = e;
                    lsum += e;
                }
                l_p += lsum;
#pragma unroll
                for (int tb = 0; tb < 4; ++tb) {
                    bf16x4 pkv;
#pragma unroll
                    for (int r = 0; r < 4; ++r) pkv[r] = (__bf16)pr[tb * 4 + r];
                    *(bf16x4*)(ps + lq * 152 + tb * 32 + g * 8) = pkv;
                }
            }

            __builtin_amdgcn_s_setprio(1);
#pragma unroll
            for (int ks = 0; ks < 2; ++ks) {
                bf16x8 pa0 = *(const bf16x8*)(ps0 + lq * 152 + ks * 64 + g * 16);
                bf16x8 pa1 = *(const bf16x8*)(ps1 + lq * 152 + ks * 64 + g * 16);
#pragma unroll
                for (int nb = 0; nb < 8; ++nb) {
                    int d = nb * 16 + lq;
                    bf16x8 vf = *(const bf16x8*)((const char*)Vs + d * 128 + ((ks * 64 + g * 16) ^ ((d & 7) << 4)));
                    acc0[nb] = __builtin_amdgcn_mfma_f32_16x16x32_bf16(pa0, vf, acc0[nb], 0, 0, 0);
                    acc1[nb] = __builtin_amdgcn_mfma_f32_16x16x32_bf16(pa1, vf, acc1[nb], 0, 0, 0);
                }
            }
            __builtin_amdgcn_s_setprio(0);
        }
        __builtin_amdgcn_sched_barrier(0);
    }

    l0 += __shfl_xor(l0, 16); l0 += __shfl_xor(l0, 32);
    l1 += __shfl_xor(l1, 16); l1 += __shfl_xor(l1, 32);
    float rl0 = 1.f / l0, rl1 = 1.f / l1;
#pragma unroll
    for (int r = 0; r < 4; ++r) {
        float rr0 = __shfl(rl0, g * 4 + r);
        float rr1 = __shfl(rl1, g * 4 + r);
        size_t row0 = (size_t)(b * S) + wqmin + g * 4 + r;
        __bf16* orow0 = outb + row0 * 4096 + h * D;
        __bf16* orow1 = orow0 + (size_t)16 * 4096;
#pragma unroll
        for (int nb = 0; nb < 8; ++nb) {
            orow0[nb * 16 + lq] = (__bf16)(acc0[nb][r] * rr0);
            orow1[nb * 16 + lq] = (__bf16)(acc1[nb][r] * rr1);
        }
    }
}

// ---------------- launch ----------------
extern "C" void kernel_launch(void* const* d_in, const int* in_sizes, int n_in,
                              void* d_out, int out_size, void* d_ws, size_t ws_size,
                              hipStream_t stream) {
    (void)in_sizes; (void)n_in; (void)out_size; (void)ws_size;
    const float* q       = (const float*)d_in[0];
    const float* w_qkv   = (const float*)d_in[1];
    const float* w_dense = (const float*)d_in[2];
    float* out = (float*)d_out;
    char* ws = (char*)d_ws;

    __bf16* qbf      = (__bf16*)(ws);
    __bf16* wqkvbf   = (__bf16*)(ws + 33554432ULL);
    __bf16* wdensebf = (__bf16*)(ws + 83886080ULL);
    __bf16* qkvbf    = (__bf16*)(ws + 117440512ULL);
    __bf16* vtbf     = (__bf16*)(ws + 167772160ULL);
    __bf16* attnbf   = (__bf16*)(ws + 176160768ULL);

    cast_f32_bf16<<<8192, 256, 0, stream>>>(q, qbf, 2097152);
    cast_f32_bf16<<<12288, 256, 0, stream>>>(w_qkv, wqkvbf, 3145728);
    cast_f32_bf16<<<8192, 256, 0, stream>>>(w_dense, wdensebf, 2097152);

    gemm_bt<1><<<dim3(48, 32), 256, 0, stream>>>(qbf, wqkvbf, (void*)qkvbf, 4096, 6144, 4096);
    transpose_v<<<dim3(32, 32), 256, 0, stream>>>(qkvbf, vtbf);
    attn_kernel<<<1024, 256, 0, stream>>>(qkvbf, vtbf, attnbf);
    gemm256<0><<<dim3(16, 16), 512, 0, stream>>>(attnbf, wdensebf, (void*)out, 4096, 4096, 4096);
}

// Round 18
// 648.569 us; speedup vs baseline: 1.1543x; 1.0020x over previous
//
#include <hip/hip_runtime.h>
#include <hip/hip_bf16.h>

typedef __bf16 bf16x8 __attribute__((ext_vector_type(8)));
typedef __bf16 bf16x4 __attribute__((ext_vector_type(4)));
typedef float  f32x4  __attribute__((ext_vector_type(4)));

typedef __attribute__((address_space(3))) void lds_vp;
typedef const __attribute__((address_space(1))) void gbl_vp;

// ---------------- cast fp32 -> bf16, 8 elems/thread ----------------
__global__ void cast_f32_bf16(const float* __restrict__ src, __bf16* __restrict__ dst, int n8) {
    int i = blockIdx.x * 256 + threadIdx.x;
    if (i >= n8) return;
    const float4* s = (const float4*)src;
    float4 a = s[2 * i], b = s[2 * i + 1];
    bf16x8 o;
    o[0] = (__bf16)a.x; o[1] = (__bf16)a.y; o[2] = (__bf16)a.z; o[3] = (__bf16)a.w;
    o[4] = (__bf16)b.x; o[5] = (__bf16)b.y; o[6] = (__bf16)b.z; o[7] = (__bf16)b.w;
    ((bf16x8*)dst)[i] = o;
}

// ---------------- 128x128 2-phase GEMM, global_load_lds staging (R14-proven) -----
template <int OUT_BF16>
__global__ __launch_bounds__(256)
void gemm_bt(const __bf16* __restrict__ A, const __bf16* __restrict__ Bm,
             void* __restrict__ Cout, int M, int N, int K) {
    __shared__ __bf16 As[128 * 64];
    __shared__ __bf16 Bs[128 * 64];
    const int tid = threadIdx.x;
    const int lane = tid & 63, wid = tid >> 6;
    const int g = lane >> 4, lq = lane & 15;
    const int wr = wid >> 1, wc = wid & 1;
    const size_t brow = (size_t)blockIdx.y * 128, bcol = (size_t)blockIdx.x * 128;
    f32x4 acc[4][4] = {};
    const int nkt = K >> 6;

    const int srow8 = lane >> 3;
    const int scol  = ((lane & 7) ^ srow8) << 3;

    for (int kt = 0; kt < nkt; ++kt) {
        __syncthreads();
#pragma unroll
        for (int j = 0; j < 4; ++j) {
            const int rb = (j * 4 + wid) * 8;
            const __bf16* sa = A + (brow + rb + srow8) * (size_t)K + (size_t)kt * 64 + scol;
            const __bf16* sb = Bm + (bcol + rb + srow8) * (size_t)K + (size_t)kt * 64 + scol;
            __builtin_amdgcn_global_load_lds((gbl_vp*)sa, (lds_vp*)(As + rb * 64), 16, 0, 0);
            __builtin_amdgcn_global_load_lds((gbl_vp*)sb, (lds_vp*)(Bs + rb * 64), 16, 0, 0);
        }
        asm volatile("s_waitcnt vmcnt(0)" ::: "memory");
        __syncthreads();
#pragma unroll
        for (int ks = 0; ks < 2; ++ks) {
            bf16x8 af[4], bfr[4];
            const int kb = ks * 64 + g * 16;
#pragma unroll
            for (int i = 0; i < 4; ++i) {
                int row = wr * 64 + i * 16 + lq;
                af[i] = *(const bf16x8*)((const char*)As + row * 128 + (kb ^ ((row & 7) << 4)));
            }
#pragma unroll
            for (int j = 0; j < 4; ++j) {
                int row = wc * 64 + j * 16 + lq;
                bfr[j] = *(const bf16x8*)((const char*)Bs + row * 128 + (kb ^ ((row & 7) << 4)));
            }
#pragma unroll
            for (int i = 0; i < 4; ++i)
#pragma unroll
                for (int j = 0; j < 4; ++j)
                    acc[i][j] = __builtin_amdgcn_mfma_f32_16x16x32_bf16(af[i], bfr[j], acc[i][j], 0, 0, 0);
        }
    }
#pragma unroll
    for (int i = 0; i < 4; ++i) {
#pragma unroll
        for (int r = 0; r < 4; ++r) {
            size_t row = brow + wr * 64 + i * 16 + g * 4 + r;
#pragma unroll
            for (int j = 0; j < 4; ++j) {
                size_t col = bcol + wc * 64 + j * 16 + lq;
                float v = acc[i][j][r];
                if (OUT_BF16) ((__bf16*)Cout)[row * N + col] = (__bf16)v;
                else          ((float*)Cout)[row * N + col] = v;
            }
        }
    }
}

// ---------------- 256x256 8-phase GEMM (R8-proven; ~137us on gemm2) -------------
__device__ __forceinline__ void stage_half(const __bf16* __restrict__ g, int K, int kt,
                                           __bf16* lds_tile, int h, int w, int l) {
#pragma unroll
    for (int j = 0; j < 2; ++j) {
        const int rih = (j * 8 + w) * 8 + (l >> 3);
        const __bf16* src = g + (size_t)(h * 128 + rih) * K + kt * 64 + (((l & 7) ^ (l >> 3)) << 3);
        __bf16* dst = lds_tile + h * 8192 + (j * 8 + w) * 512;
        __builtin_amdgcn_global_load_lds((gbl_vp*)src, (lds_vp*)dst, 16, 0, 0);
    }
}

__device__ __forceinline__ bf16x8 lds_frag(const __bf16* base, int row, int kb) {
    return *(const bf16x8*)((const char*)base + row * 128 + (kb ^ ((row & 7) << 4)));
}

template <int OUT_BF16>
__global__ __launch_bounds__(512, 2)
void gemm256(const __bf16* __restrict__ A, const __bf16* __restrict__ Bm,
             void* __restrict__ Cout, int M, int N, int K) {
    __shared__ __bf16 As[2][256 * 64];
    __shared__ __bf16 Bs[2][256 * 64];
    const int tid = threadIdx.x;
    const int lane = tid & 63, wid = tid >> 6;
    const int g = lane >> 4, lq = lane & 15;
    const int wm = wid >> 2, wn = wid & 3;
    const size_t brow = (size_t)blockIdx.y * 256, bcol = (size_t)blockIdx.x * 256;
    const __bf16* Ag = A + brow * K;
    const __bf16* Bg = Bm + bcol * K;
    const int nkt = K >> 6, niter = nkt >> 1;

    f32x4 acc[8][4] = {};

    stage_half(Ag, K, 0, &As[0][0], 0, wid, lane);
    stage_half(Bg, K, 0, &Bs[0][0], 0, wid, lane);
    stage_half(Ag, K, 0, &As[0][0], 1, wid, lane);
    stage_half(Bg, K, 0, &Bs[0][0], 1, wid, lane);

    const int arow0 = wm * 128 + lq;
    const int brow0 = wn * 64 + lq;

    for (int it = 0; it < niter; ++it) {
        const int t0 = 2 * it;
#pragma unroll
        for (int hf = 0; hf < 2; ++hf) {
            const __bf16* SA = &As[hf][0];
            const __bf16* SB = &Bs[hf][0];
            __bf16* DA = &As[hf ^ 1][0];
            __bf16* DB = &Bs[hf ^ 1][0];
            const int tstage = t0 + 1 + hf;
            const bool dostage = (tstage < nkt);
            bf16x8 bfr[4][2];

            if (dostage) stage_half(Ag, K, tstage, DA, 0, wid, lane);
            __builtin_amdgcn_sched_barrier(0);
            if (dostage) asm volatile("s_waitcnt vmcnt(2)" ::: "memory");
            else         asm volatile("s_waitcnt vmcnt(0)" ::: "memory");
            __builtin_amdgcn_s_barrier();
            __builtin_amdgcn_sched_barrier(0);
#pragma unroll
            for (int n = 0; n < 4; ++n)
#pragma unroll
                for (int kk = 0; kk < 2; ++kk)
                    bfr[n][kk] = lds_frag(SB, brow0 + n * 16, kk * 64 + g * 16);
            {
                bf16x8 afr[2][2];
#pragma unroll
                for (int mm = 0; mm < 2; ++mm)
#pragma unroll
                    for (int kk = 0; kk < 2; ++kk)
                        afr[mm][kk] = lds_frag(SA, arow0 + mm * 16, kk * 64 + g * 16);
                __builtin_amdgcn_s_setprio(1);
#pragma unroll
                for (int kk = 0; kk < 2; ++kk)
#pragma unroll
                    for (int n = 0; n < 4; ++n)
#pragma unroll
                        for (int mm = 0; mm < 2; ++mm)
                            acc[mm][n] = __builtin_amdgcn_mfma_f32_16x16x32_bf16(afr[mm][kk], bfr[n][kk], acc[mm][n], 0, 0, 0);
                __builtin_amdgcn_s_setprio(0);
            }
            __builtin_amdgcn_sched_barrier(0);
            __builtin_amdgcn_s_barrier();
            __builtin_amdgcn_sched_barrier(0);

#pragma unroll
            for (int q = 1; q < 4; ++q) {
                bf16x8 afr[2][2];
#pragma unroll
                for (int mm = 0; mm < 2; ++mm)
#pragma unroll
                    for (int kk = 0; kk < 2; ++kk)
                        afr[mm][kk] = lds_frag(SA, arow0 + (q * 2 + mm) * 16, kk * 64 + g * 16);
                if (dostage) {
                    if (q == 1)      stage_half(Bg, K, tstage, DB, 0, wid, lane);
                    else if (q == 2) stage_half(Ag, K, tstage, DA, 1, wid, lane);
                    else             stage_half(Bg, K, tstage, DB, 1, wid, lane);
                }
                __builtin_amdgcn_sched_barrier(0);
                __builtin_amdgcn_s_barrier();
                __builtin_amdgcn_sched_barrier(0);
                __builtin_amdgcn_s_setprio(1);
#pragma unroll
                for (int kk = 0; kk < 2; ++kk)
#pragma unroll
                    for (int n = 0; n < 4; ++n)
#pragma unroll
                        for (int mm = 0; mm < 2; ++mm)
                            acc[q * 2 + mm][n] = __builtin_amdgcn_mfma_f32_16x16x32_bf16(afr[mm][kk], bfr[n][kk], acc[q * 2 + mm][n], 0, 0, 0);
                __builtin_amdgcn_s_setprio(0);
                __builtin_amdgcn_sched_barrier(0);
                __builtin_amdgcn_s_barrier();
                __builtin_amdgcn_sched_barrier(0);
            }
        }
    }

#pragma unroll
    for (int m = 0; m < 8; ++m) {
#pragma unroll
        for (int r = 0; r < 4; ++r) {
            size_t row = brow + wm * 128 + m * 16 + g * 4 + r;
#pragma unroll
            for (int n = 0; n < 4; ++n) {
                size_t col = bcol + wn * 64 + n * 16 + lq;
                float v = acc[m][n][r];
                if (OUT_BF16) ((__bf16*)Cout)[row * N + col] = (__bf16)v;
                else          ((float*)Cout)[row * N + col] = v;
            }
        }
    }
}

// ---------------- V transpose: qkv V-part -> vt[(b*8+kh)*128+d][t] ----------------
__global__ __launch_bounds__(256)
void transpose_v(const __bf16* __restrict__ qkv, __bf16* __restrict__ vt) {
    constexpr int S = 2048, QKVN = 6144;
    __shared__ __bf16 tile[64][72];
    const int tt = blockIdx.x;
    const int yz = blockIdx.y;
    const int dh = yz & 1, bkh = yz >> 1;
    const int b = bkh >> 3, kh = bkh & 7;
    const int tid = threadIdx.x;
#pragma unroll
    for (int i = 0; i < 2; ++i) {
        int flat = i * 2048 + tid * 8;
        int r = flat >> 6, c0 = flat & 63;
        const __bf16* src = qkv + ((size_t)b * S + tt * 64 + r) * QKVN + 5120 + kh * 128 + dh * 64 + c0;
        *(bf16x8*)&tile[r][c0] = *(const bf16x8*)src;
    }
    __syncthreads();
#pragma unroll
    for (int i = 0; i < 2; ++i) {
        int flat = i * 2048 + tid * 8;
        int d = flat >> 6, t0 = flat & 63;
        bf16x8 pk;
#pragma unroll
        for (int e = 0; e < 8; ++e) pk[e] = tile[t0 + e][d];
        __bf16* dst = vt + ((size_t)(b * 8 + kh) * 128 + dh * 64 + d) * S + tt * 64 + t0;
        *(bf16x8*)dst = pk;
    }
}

// ---------------- flash attention v11: 4 waves, 40960B LDS -> 4 blocks/CU -------
// R7 structure; ONE change: Ps shrunk to ONE frag/wave (4x16x128B = 8KB, was
// 19KB) with XOR (lq&7)<<4 swizzle (both sides), PV per-frag sequential
// (softmax f -> Ps write -> lgkmcnt -> PV f; same-wave DS order, no barrier).
// LDS = 16384+16384+8192 = 40960 exactly -> 4 blocks/CU (was 3), 1024-block
// grid = one full round.
__global__ __launch_bounds__(256, 2)
void attn_kernel(const __bf16* __restrict__ qkv, const __bf16* __restrict__ vt,
                 __bf16* __restrict__ outb) {
    constexpr int S = 2048, D = 128, QKVN = 6144;
    const int p = blockIdx.x;
    const int kh = p & 7;
    const int j = p >> 3;
    const int qt = 15 - (j >> 3);
    const int b  = (j >> 2) & 1;
    const int g4 = j & 3;
    const int h  = kh * 4 + g4;
    const int tid = threadIdx.x, lane = tid & 63, w = tid >> 6;
    const int g = lane >> 4, lq = lane & 15;

    __shared__ __bf16 Ks[64 * 128];          // 16384B
    __shared__ __bf16 Vs[128 * 64];          // 16384B
    __shared__ char   PsRaw[4][16 * 128];    // 8192B: per-wave single-frag P

    const int wqmin = qt * 128 + w * 32;
    const int qg0 = wqmin + lq;
    const int qg1 = qg0 + 16;

    const __bf16* qrow = qkv + ((size_t)(b * S) + wqmin + lq) * QKVN + h * D;
    bf16x8 qf0[4], qf1[4];
#pragma unroll
    for (int ks = 0; ks < 4; ++ks) {
        qf0[ks] = *(const bf16x8*)(qrow + ks * 32 + g * 8);
        qf1[ks] = *(const bf16x8*)(qrow + (size_t)16 * QKVN + ks * 32 + g * 8);
    }

    const char* kbase = (const char*)qkv + ((size_t)(b * S) * QKVN + 4096 + kh * D) * 2;
    const char* vbase = (const char*)vt + ((size_t)(b * 8 + kh) * D * S) * 2;

    f32x4 acc0[8] = {}, acc1[8] = {};
    float m0 = -1e30f, l0 = 0.f, m1 = -1e30f, l1 = 0.f;
    const float scale2 = 0.12753102494f;

    const int krow0 = tid >> 4;
    const int kcolb = (tid & 15) * 16;
    const int vrow0 = tid >> 3;
    const int vcolb = (tid & 7) * 16;

    const int ktmax = 2 * qt + 1;
    int4 pk[4], pv[4];
#pragma unroll
    for (int is = 0; is < 4; ++is) {
        pk[is] = *(const int4*)(kbase + (size_t)(is * 16 + krow0) * QKVN * 2 + kcolb);
        pv[is] = *(const int4*)(vbase + (size_t)(is * 32 + vrow0) * S * 2 + vcolb);
    }

    char* ps = &PsRaw[w][0];
    const int psw = (lq & 7) << 4;           // Ps XOR swizzle (both sides)

    for (int kt = 0; kt <= ktmax; ++kt) {
        __builtin_amdgcn_s_barrier();
#pragma unroll
        for (int is = 0; is < 4; ++is) {
            int row = is * 16 + krow0;
            *(int4*)((char*)Ks + row * 256 + (kcolb ^ ((row & 15) << 4))) = pk[is];
            int d = is * 32 + vrow0;
            *(int4*)((char*)Vs + d * 128 + (vcolb ^ ((d & 7) << 4))) = pv[is];
        }
        if (kt < ktmax) {
#pragma unroll
            for (int is = 0; is < 4; ++is) {
                pk[is] = *(const int4*)(kbase + (size_t)((kt + 1) * 64 + is * 16 + krow0) * QKVN * 2 + kcolb);
                pv[is] = *(const int4*)(vbase + ((size_t)(is * 32 + vrow0) * S + (kt + 1) * 64) * 2 + vcolb);
            }
        }
        __builtin_amdgcn_sched_barrier(0);
        asm volatile("s_waitcnt lgkmcnt(0)" ::: "memory");
        __builtin_amdgcn_sched_barrier(0);
        __builtin_amdgcn_s_barrier();
        __builtin_amdgcn_sched_barrier(0);

        if (kt * 64 <= wqmin + 31) {
            f32x4 sc0[4], sc1[4];
            __builtin_amdgcn_s_setprio(1);
#pragma unroll
            for (int tb = 0; tb < 4; ++tb) {
                f32x4 s0 = {0.f, 0.f, 0.f, 0.f}, s1 = {0.f, 0.f, 0.f, 0.f};
                const int trow = tb * 16 + lq;
                const int rsw = (trow & 15) << 4;
#pragma unroll
                for (int ks = 0; ks < 4; ++ks) {
                    bf16x8 kf = *(const bf16x8*)((const char*)Ks + trow * 256 + ((ks * 64 + g * 16) ^ rsw));
                    s0 = __builtin_amdgcn_mfma_f32_16x16x32_bf16(kf, qf0[ks], s0, 0, 0, 0);
                    s1 = __builtin_amdgcn_mfma_f32_16x16x32_bf16(kf, qf1[ks], s1, 0, 0, 0);
                }
                sc0[tb] = s0; sc1[tb] = s1;
            }
            __builtin_amdgcn_s_setprio(0);

#pragma unroll
            for (int f = 0; f < 2; ++f) {
                f32x4* sc = f ? sc1 : sc0;
                float& m_r = f ? m1 : m0;
                float& l_p = f ? l1 : l0;
                f32x4* acc = f ? acc1 : acc0;
                const int qg = f ? qg1 : qg0;
                const bool domask = (kt * 64 + 63 > qg - lq);

                float pr[16];
                float rowmax = -1e30f;
#pragma unroll
                for (int tb = 0; tb < 4; ++tb)
#pragma unroll
                    for (int r = 0; r < 4; ++r) {
                        float sv = sc[tb][r] * scale2;
                        if (domask) {
                            int tg = kt * 64 + tb * 16 + g * 4 + r;
                            sv = (tg <= qg) ? sv : -1e30f;
                        }
                        pr[tb * 4 + r] = sv;
                        rowmax = fmaxf(rowmax, sv);
                    }
                rowmax = fmaxf(rowmax, __shfl_xor(rowmax, 16));
                rowmax = fmaxf(rowmax, __shfl_xor(rowmax, 32));
                if (!__all(rowmax - m_r <= 11.0f)) {
                    float m_new = fmaxf(m_r, rowmax);
                    float alpha = exp2f(m_r - m_new);
                    l_p *= alpha;
#pragma unroll
                    for (int r = 0; r < 4; ++r) {
                        float ar = __shfl(alpha, g * 4 + r);
#pragma unroll
                        for (int nb = 0; nb < 8; ++nb) acc[nb][r] *= ar;
                    }
                    m_r = m_new;
                }
                float lsum = 0.f;
#pragma unroll
                for (int i = 0; i < 16; ++i) {
                    float e = exp2f(pr[i] - m_r);
                    pr[i] = e;
                    lsum += e;
                }
                l_p += lsum;

                // P -> per-wave single-frag Ps (stride 128, XOR swizzle)
#pragma unroll
                for (int tb = 0; tb < 4; ++tb) {
                    bf16x4 pkv;
#pragma unroll
                    for (int r = 0; r < 4; ++r) pkv[r] = (__bf16)pr[tb * 4 + r];
                    *(bf16x4*)(ps + lq * 128 + ((tb * 32 + g * 8) ^ psw)) = pkv;
                }
                asm volatile("s_waitcnt lgkmcnt(0)" ::: "memory");
                __builtin_amdgcn_sched_barrier(0);

                // PV for this frag
                __builtin_amdgcn_s_setprio(1);
#pragma unroll
                for (int ks = 0; ks < 2; ++ks) {
                    bf16x8 pa = *(const bf16x8*)(ps + lq * 128 + ((ks * 64 + g * 16) ^ psw));
#pragma unroll
                    for (int nb = 0; nb < 8; ++nb) {
                        int d = nb * 16 + lq;
                        bf16x8 vf = *(const bf16x8*)((const char*)Vs + d * 128 + ((ks * 64 + g * 16) ^ ((d & 7) << 4)));
                        acc[nb] = __builtin_amdgcn_mfma_f32_16x16x32_bf16(pa, vf, acc[nb], 0, 0, 0);
                    }
                }
                __builtin_amdgcn_s_setprio(0);
                __builtin_amdgcn_sched_barrier(0);
            }
        }
        __builtin_amdgcn_sched_barrier(0);
    }

    l0 += __shfl_xor(l0, 16); l0 += __shfl_xor(l0, 32);
    l1 += __shfl_xor(l1, 16); l1 += __shfl_xor(l1, 32);
    float rl0 = 1.f / l0, rl1 = 1.f / l1;
#pragma unroll
    for (int r = 0; r < 4; ++r) {
        float rr0 = __shfl(rl0, g * 4 + r);
        float rr1 = __shfl(rl1, g * 4 + r);
        size_t row0 = (size_t)(b * S) + wqmin + g * 4 + r;
        __bf16* orow0 = outb + row0 * 4096 + h * D;
        __bf16* orow1 = orow0 + (size_t)16 * 4096;
#pragma unroll
        for (int nb = 0; nb < 8; ++nb) {
            orow0[nb * 16 + lq] = (__bf16)(acc0[nb][r] * rr0);
            orow1[nb * 16 + lq] = (__bf16)(acc1[nb][r] * rr1);
        }
    }
}

// ---------------- launch ----------------
extern "C" void kernel_launch(void* const* d_in, const int* in_sizes, int n_in,
                              void* d_out, int out_size, void* d_ws, size_t ws_size,
                              hipStream_t stream) {
    (void)in_sizes; (void)n_in; (void)out_size; (void)ws_size;
    const float* q       = (const float*)d_in[0];
    const float* w_qkv   = (const float*)d_in[1];
    const float* w_dense = (const float*)d_in[2];
    float* out = (float*)d_out;
    char* ws = (char*)d_ws;

    __bf16* qbf      = (__bf16*)(ws);
    __bf16* wqkvbf   = (__bf16*)(ws + 33554432ULL);
    __bf16* wdensebf = (__bf16*)(ws + 83886080ULL);
    __bf16* qkvbf    = (__bf16*)(ws + 117440512ULL);
    __bf16* vtbf     = (__bf16*)(ws + 167772160ULL);
    __bf16* attnbf   = (__bf16*)(ws + 176160768ULL);

    cast_f32_bf16<<<8192, 256, 0, stream>>>(q, qbf, 2097152);
    cast_f32_bf16<<<12288, 256, 0, stream>>>(w_qkv, wqkvbf, 3145728);
    cast_f32_bf16<<<8192, 256, 0, stream>>>(w_dense, wdensebf, 2097152);

    gemm_bt<1><<<dim3(48, 32), 256, 0, stream>>>(qbf, wqkvbf, (void*)qkvbf, 4096, 6144, 4096);
    transpose_v<<<dim3(32, 32), 256, 0, stream>>>(qkvbf, vtbf);
    attn_kernel<<<1024, 256, 0, stream>>>(qkvbf, vtbf, attnbf);
    gemm256<0><<<dim3(16, 16), 512, 0, stream>>>(attnbf, wdensebf, (void*)out, 4096, 4096, 4096);
}

// Round 19
// 643.594 us; speedup vs baseline: 1.1632x; 1.0077x over previous
//
#include <hip/hip_runtime.h>
#include <hip/hip_bf16.h>

typedef __bf16 bf16x8 __attribute__((ext_vector_type(8)));
typedef __bf16 bf16x4 __attribute__((ext_vector_type(4)));
typedef float  f32x4  __attribute__((ext_vector_type(4)));

typedef __attribute__((address_space(3))) void lds_vp;
typedef const __attribute__((address_space(1))) void gbl_vp;

// ---------------- fused cast fp32 -> bf16 (q, w_qkv, w_dense in one dispatch) ----
// Segment bounds in float8 units: q 2097152, w_qkv 3145728, w_dense 2097152.
__global__ void cast_all(const float* __restrict__ q, const float* __restrict__ wq,
                         const float* __restrict__ wd, __bf16* __restrict__ oq,
                         __bf16* __restrict__ owq, __bf16* __restrict__ owd) {
    int i = blockIdx.x * 256 + threadIdx.x;          // 0 .. 7340031
    const float* src;
    __bf16* dst;
    int off;
    if (i < 2097152)      { src = q;  dst = oq;  off = i; }
    else if (i < 5242880) { src = wq; dst = owq; off = i - 2097152; }
    else                  { src = wd; dst = owd; off = i - 5242880; }
    const float4* s = (const float4*)src;
    float4 a = s[2 * off], b = s[2 * off + 1];
    bf16x8 o;
    o[0] = (__bf16)a.x; o[1] = (__bf16)a.y; o[2] = (__bf16)a.z; o[3] = (__bf16)a.w;
    o[4] = (__bf16)b.x; o[5] = (__bf16)b.y; o[6] = (__bf16)b.z; o[7] = (__bf16)b.w;
    ((bf16x8*)dst)[off] = o;
}

// ---------------- 128x128 2-phase GEMM, global_load_lds staging (R14-proven) -----
template <int OUT_BF16>
__global__ __launch_bounds__(256)
void gemm_bt(const __bf16* __restrict__ A, const __bf16* __restrict__ Bm,
             void* __restrict__ Cout, int M, int N, int K) {
    __shared__ __bf16 As[128 * 64];
    __shared__ __bf16 Bs[128 * 64];
    const int tid = threadIdx.x;
    const int lane = tid & 63, wid = tid >> 6;
    const int g = lane >> 4, lq = lane & 15;
    const int wr = wid >> 1, wc = wid & 1;
    const size_t brow = (size_t)blockIdx.y * 128, bcol = (size_t)blockIdx.x * 128;
    f32x4 acc[4][4] = {};
    const int nkt = K >> 6;

    const int srow8 = lane >> 3;
    const int scol  = ((lane & 7) ^ srow8) << 3;

    for (int kt = 0; kt < nkt; ++kt) {
        __syncthreads();
#pragma unroll
        for (int j = 0; j < 4; ++j) {
            const int rb = (j * 4 + wid) * 8;
            const __bf16* sa = A + (brow + rb + srow8) * (size_t)K + (size_t)kt * 64 + scol;
            const __bf16* sb = Bm + (bcol + rb + srow8) * (size_t)K + (size_t)kt * 64 + scol;
            __builtin_amdgcn_global_load_lds((gbl_vp*)sa, (lds_vp*)(As + rb * 64), 16, 0, 0);
            __builtin_amdgcn_global_load_lds((gbl_vp*)sb, (lds_vp*)(Bs + rb * 64), 16, 0, 0);
        }
        asm volatile("s_waitcnt vmcnt(0)" ::: "memory");
        __syncthreads();
#pragma unroll
        for (int ks = 0; ks < 2; ++ks) {
            bf16x8 af[4], bfr[4];
            const int kb = ks * 64 + g * 16;
#pragma unroll
            for (int i = 0; i < 4; ++i) {
                int row = wr * 64 + i * 16 + lq;
                af[i] = *(const bf16x8*)((const char*)As + row * 128 + (kb ^ ((row & 7) << 4)));
            }
#pragma unroll
            for (int j = 0; j < 4; ++j) {
                int row = wc * 64 + j * 16 + lq;
                bfr[j] = *(const bf16x8*)((const char*)Bs + row * 128 + (kb ^ ((row & 7) << 4)));
            }
#pragma unroll
            for (int i = 0; i < 4; ++i)
#pragma unroll
                for (int j = 0; j < 4; ++j)
                    acc[i][j] = __builtin_amdgcn_mfma_f32_16x16x32_bf16(af[i], bfr[j], acc[i][j], 0, 0, 0);
        }
    }
#pragma unroll
    for (int i = 0; i < 4; ++i) {
#pragma unroll
        for (int r = 0; r < 4; ++r) {
            size_t row = brow + wr * 64 + i * 16 + g * 4 + r;
#pragma unroll
            for (int j = 0; j < 4; ++j) {
                size_t col = bcol + wc * 64 + j * 16 + lq;
                float v = acc[i][j][r];
                if (OUT_BF16) ((__bf16*)Cout)[row * N + col] = (__bf16)v;
                else          ((float*)Cout)[row * N + col] = v;
            }
        }
    }
}

// ---------------- 256x256 8-phase GEMM (R8-proven; ~137us on gemm2) -------------
__device__ __forceinline__ void stage_half(const __bf16* __restrict__ g, int K, int kt,
                                           __bf16* lds_tile, int h, int w, int l) {
#pragma unroll
    for (int j = 0; j < 2; ++j) {
        const int rih = (j * 8 + w) * 8 + (l >> 3);
        const __bf16* src = g + (size_t)(h * 128 + rih) * K + kt * 64 + (((l & 7) ^ (l >> 3)) << 3);
        __bf16* dst = lds_tile + h * 8192 + (j * 8 + w) * 512;
        __builtin_amdgcn_global_load_lds((gbl_vp*)src, (lds_vp*)dst, 16, 0, 0);
    }
}

__device__ __forceinline__ bf16x8 lds_frag(const __bf16* base, int row, int kb) {
    return *(const bf16x8*)((const char*)base + row * 128 + (kb ^ ((row & 7) << 4)));
}

template <int OUT_BF16>
__global__ __launch_bounds__(512, 2)
void gemm256(const __bf16* __restrict__ A, const __bf16* __restrict__ Bm,
             void* __restrict__ Cout, int M, int N, int K) {
    __shared__ __bf16 As[2][256 * 64];
    __shared__ __bf16 Bs[2][256 * 64];
    const int tid = threadIdx.x;
    const int lane = tid & 63, wid = tid >> 6;
    const int g = lane >> 4, lq = lane & 15;
    const int wm = wid >> 2, wn = wid & 3;
    const size_t brow = (size_t)blockIdx.y * 256, bcol = (size_t)blockIdx.x * 256;
    const __bf16* Ag = A + brow * K;
    const __bf16* Bg = Bm + bcol * K;
    const int nkt = K >> 6, niter = nkt >> 1;

    f32x4 acc[8][4] = {};

    stage_half(Ag, K, 0, &As[0][0], 0, wid, lane);
    stage_half(Bg, K, 0, &Bs[0][0], 0, wid, lane);
    stage_half(Ag, K, 0, &As[0][0], 1, wid, lane);
    stage_half(Bg, K, 0, &Bs[0][0], 1, wid, lane);

    const int arow0 = wm * 128 + lq;
    const int brow0 = wn * 64 + lq;

    for (int it = 0; it < niter; ++it) {
        const int t0 = 2 * it;
#pragma unroll
        for (int hf = 0; hf < 2; ++hf) {
            const __bf16* SA = &As[hf][0];
            const __bf16* SB = &Bs[hf][0];
            __bf16* DA = &As[hf ^ 1][0];
            __bf16* DB = &Bs[hf ^ 1][0];
            const int tstage = t0 + 1 + hf;
            const bool dostage = (tstage < nkt);
            bf16x8 bfr[4][2];

            if (dostage) stage_half(Ag, K, tstage, DA, 0, wid, lane);
            __builtin_amdgcn_sched_barrier(0);
            if (dostage) asm volatile("s_waitcnt vmcnt(2)" ::: "memory");
            else         asm volatile("s_waitcnt vmcnt(0)" ::: "memory");
            __builtin_amdgcn_s_barrier();
            __builtin_amdgcn_sched_barrier(0);
#pragma unroll
            for (int n = 0; n < 4; ++n)
#pragma unroll
                for (int kk = 0; kk < 2; ++kk)
                    bfr[n][kk] = lds_frag(SB, brow0 + n * 16, kk * 64 + g * 16);
            {
                bf16x8 afr[2][2];
#pragma unroll
                for (int mm = 0; mm < 2; ++mm)
#pragma unroll
                    for (int kk = 0; kk < 2; ++kk)
                        afr[mm][kk] = lds_frag(SA, arow0 + mm * 16, kk * 64 + g * 16);
                __builtin_amdgcn_s_setprio(1);
#pragma unroll
                for (int kk = 0; kk < 2; ++kk)
#pragma unroll
                    for (int n = 0; n < 4; ++n)
#pragma unroll
                        for (int mm = 0; mm < 2; ++mm)
                            acc[mm][n] = __builtin_amdgcn_mfma_f32_16x16x32_bf16(afr[mm][kk], bfr[n][kk], acc[mm][n], 0, 0, 0);
                __builtin_amdgcn_s_setprio(0);
            }
            __builtin_amdgcn_sched_barrier(0);
            __builtin_amdgcn_s_barrier();
            __builtin_amdgcn_sched_barrier(0);

#pragma unroll
            for (int q = 1; q < 4; ++q) {
                bf16x8 afr[2][2];
#pragma unroll
                for (int mm = 0; mm < 2; ++mm)
#pragma unroll
                    for (int kk = 0; kk < 2; ++kk)
                        afr[mm][kk] = lds_frag(SA, arow0 + (q * 2 + mm) * 16, kk * 64 + g * 16);
                if (dostage) {
                    if (q == 1)      stage_half(Bg, K, tstage, DB, 0, wid, lane);
                    else if (q == 2) stage_half(Ag, K, tstage, DA, 1, wid, lane);
                    else             stage_half(Bg, K, tstage, DB, 1, wid, lane);
                }
                __builtin_amdgcn_sched_barrier(0);
                __builtin_amdgcn_s_barrier();
                __builtin_amdgcn_sched_barrier(0);
                __builtin_amdgcn_s_setprio(1);
#pragma unroll
                for (int kk = 0; kk < 2; ++kk)
#pragma unroll
                    for (int n = 0; n < 4; ++n)
#pragma unroll
                        for (int mm = 0; mm < 2; ++mm)
                            acc[q * 2 + mm][n] = __builtin_amdgcn_mfma_f32_16x16x32_bf16(afr[mm][kk], bfr[n][kk], acc[q * 2 + mm][n], 0, 0, 0);
                __builtin_amdgcn_s_setprio(0);
                __builtin_amdgcn_sched_barrier(0);
                __builtin_amdgcn_s_barrier();
                __builtin_amdgcn_sched_barrier(0);
            }
        }
    }

#pragma unroll
    for (int m = 0; m < 8; ++m) {
#pragma unroll
        for (int r = 0; r < 4; ++r) {
            size_t row = brow + wm * 128 + m * 16 + g * 4 + r;
#pragma unroll
            for (int n = 0; n < 4; ++n) {
                size_t col = bcol + wn * 64 + n * 16 + lq;
                float v = acc[m][n][r];
                if (OUT_BF16) ((__bf16*)Cout)[row * N + col] = (__bf16)v;
                else          ((float*)Cout)[row * N + col] = v;
            }
        }
    }
}

// ---------------- V transpose: qkv V-part -> vt[(b*8+kh)*128+d][t] ----------------
__global__ __launch_bounds__(256)
void transpose_v(const __bf16* __restrict__ qkv, __bf16* __restrict__ vt) {
    constexpr int S = 2048, QKVN = 6144;
    __shared__ __bf16 tile[64][72];
    const int tt = blockIdx.x;
    const int yz = blockIdx.y;
    const int dh = yz & 1, bkh = yz >> 1;
    const int b = bkh >> 3, kh = bkh & 7;
    const int tid = threadIdx.x;
#pragma unroll
    for (int i = 0; i < 2; ++i) {
        int flat = i * 2048 + tid * 8;
        int r = flat >> 6, c0 = flat & 63;
        const __bf16* src = qkv + ((size_t)b * S + tt * 64 + r) * QKVN + 5120 + kh * 128 + dh * 64 + c0;
        *(bf16x8*)&tile[r][c0] = *(const bf16x8*)src;
    }
    __syncthreads();
#pragma unroll
    for (int i = 0; i < 2; ++i) {
        int flat = i * 2048 + tid * 8;
        int d = flat >> 6, t0 = flat & 63;
        bf16x8 pk;
#pragma unroll
        for (int e = 0; e < 8; ++e) pk[e] = tile[t0 + e][d];
        __bf16* dst = vt + ((size_t)(b * 8 + kh) * 128 + dh * 64 + d) * S + tt * 64 + t0;
        *(bf16x8*)dst = pk;
    }
}

// ---------------- flash attention v11 (R18-proven, FROZEN) ----------------------
__global__ __launch_bounds__(256, 2)
void attn_kernel(const __bf16* __restrict__ qkv, const __bf16* __restrict__ vt,
                 __bf16* __restrict__ outb) {
    constexpr int S = 2048, D = 128, QKVN = 6144;
    const int p = blockIdx.x;
    const int kh = p & 7;
    const int j = p >> 3;
    const int qt = 15 - (j >> 3);
    const int b  = (j >> 2) & 1;
    const int g4 = j & 3;
    const int h  = kh * 4 + g4;
    const int tid = threadIdx.x, lane = tid & 63, w = tid >> 6;
    const int g = lane >> 4, lq = lane & 15;

    __shared__ __bf16 Ks[64 * 128];
    __shared__ __bf16 Vs[128 * 64];
    __shared__ char   PsRaw[4][16 * 128];

    const int wqmin = qt * 128 + w * 32;
    const int qg0 = wqmin + lq;
    const int qg1 = qg0 + 16;

    const __bf16* qrow = qkv + ((size_t)(b * S) + wqmin + lq) * QKVN + h * D;
    bf16x8 qf0[4], qf1[4];
#pragma unroll
    for (int ks = 0; ks < 4; ++ks) {
        qf0[ks] = *(const bf16x8*)(qrow + ks * 32 + g * 8);
        qf1[ks] = *(const bf16x8*)(qrow + (size_t)16 * QKVN + ks * 32 + g * 8);
    }

    const char* kbase = (const char*)qkv + ((size_t)(b * S) * QKVN + 4096 + kh * D) * 2;
    const char* vbase = (const char*)vt + ((size_t)(b * 8 + kh) * D * S) * 2;

    f32x4 acc0[8] = {}, acc1[8] = {};
    float m0 = -1e30f, l0 = 0.f, m1 = -1e30f, l1 = 0.f;
    const float scale2 = 0.12753102494f;

    const int krow0 = tid >> 4;
    const int kcolb = (tid & 15) * 16;
    const int vrow0 = tid >> 3;
    const int vcolb = (tid & 7) * 16;

    const int ktmax = 2 * qt + 1;
    int4 pk[4], pv[4];
#pragma unroll
    for (int is = 0; is < 4; ++is) {
        pk[is] = *(const int4*)(kbase + (size_t)(is * 16 + krow0) * QKVN * 2 + kcolb);
        pv[is] = *(const int4*)(vbase + (size_t)(is * 32 + vrow0) * S * 2 + vcolb);
    }

    char* ps = &PsRaw[w][0];
    const int psw = (lq & 7) << 4;

    for (int kt = 0; kt <= ktmax; ++kt) {
        __builtin_amdgcn_s_barrier();
#pragma unroll
        for (int is = 0; is < 4; ++is) {
            int row = is * 16 + krow0;
            *(int4*)((char*)Ks + row * 256 + (kcolb ^ ((row & 15) << 4))) = pk[is];
            int d = is * 32 + vrow0;
            *(int4*)((char*)Vs + d * 128 + (vcolb ^ ((d & 7) << 4))) = pv[is];
        }
        if (kt < ktmax) {
#pragma unroll
            for (int is = 0; is < 4; ++is) {
                pk[is] = *(const int4*)(kbase + (size_t)((kt + 1) * 64 + is * 16 + krow0) * QKVN * 2 + kcolb);
                pv[is] = *(const int4*)(vbase + ((size_t)(is * 32 + vrow0) * S + (kt + 1) * 64) * 2 + vcolb);
            }
        }
        __builtin_amdgcn_sched_barrier(0);
        asm volatile("s_waitcnt lgkmcnt(0)" ::: "memory");
        __builtin_amdgcn_sched_barrier(0);
        __builtin_amdgcn_s_barrier();
        __builtin_amdgcn_sched_barrier(0);

        if (kt * 64 <= wqmin + 31) {
            f32x4 sc0[4], sc1[4];
            __builtin_amdgcn_s_setprio(1);
#pragma unroll
            for (int tb = 0; tb < 4; ++tb) {
                f32x4 s0 = {0.f, 0.f, 0.f, 0.f}, s1 = {0.f, 0.f, 0.f, 0.f};
                const int trow = tb * 16 + lq;
                const int rsw = (trow & 15) << 4;
#pragma unroll
                for (int ks = 0; ks < 4; ++ks) {
                    bf16x8 kf = *(const bf16x8*)((const char*)Ks + trow * 256 + ((ks * 64 + g * 16) ^ rsw));
                    s0 = __builtin_amdgcn_mfma_f32_16x16x32_bf16(kf, qf0[ks], s0, 0, 0, 0);
                    s1 = __builtin_amdgcn_mfma_f32_16x16x32_bf16(kf, qf1[ks], s1, 0, 0, 0);
                }
                sc0[tb] = s0; sc1[tb] = s1;
            }
            __builtin_amdgcn_s_setprio(0);

#pragma unroll
            for (int f = 0; f < 2; ++f) {
                f32x4* sc = f ? sc1 : sc0;
                float& m_r = f ? m1 : m0;
                float& l_p = f ? l1 : l0;
                f32x4* acc = f ? acc1 : acc0;
                const int qg = f ? qg1 : qg0;
                const bool domask = (kt * 64 + 63 > qg - lq);

                float pr[16];
                float rowmax = -1e30f;
#pragma unroll
                for (int tb = 0; tb < 4; ++tb)
#pragma unroll
                    for (int r = 0; r < 4; ++r) {
                        float sv = sc[tb][r] * scale2;
                        if (domask) {
                            int tg = kt * 64 + tb * 16 + g * 4 + r;
                            sv = (tg <= qg) ? sv : -1e30f;
                        }
                        pr[tb * 4 + r] = sv;
                        rowmax = fmaxf(rowmax, sv);
                    }
                rowmax = fmaxf(rowmax, __shfl_xor(rowmax, 16));
                rowmax = fmaxf(rowmax, __shfl_xor(rowmax, 32));
                if (!__all(rowmax - m_r <= 11.0f)) {
                    float m_new = fmaxf(m_r, rowmax);
                    float alpha = exp2f(m_r - m_new);
                    l_p *= alpha;
#pragma unroll
                    for (int r = 0; r < 4; ++r) {
                        float ar = __shfl(alpha, g * 4 + r);
#pragma unroll
                        for (int nb = 0; nb < 8; ++nb) acc[nb][r] *= ar;
                    }
                    m_r = m_new;
                }
                float lsum = 0.f;
#pragma unroll
                for (int i = 0; i < 16; ++i) {
                    float e = exp2f(pr[i] - m_r);
                    pr[i] = e;
                    lsum += e;
                }
                l_p += lsum;

#pragma unroll
                for (int tb = 0; tb < 4; ++tb) {
                    bf16x4 pkv;
#pragma unroll
                    for (int r = 0; r < 4; ++r) pkv[r] = (__bf16)pr[tb * 4 + r];
                    *(bf16x4*)(ps + lq * 128 + ((tb * 32 + g * 8) ^ psw)) = pkv;
                }
                asm volatile("s_waitcnt lgkmcnt(0)" ::: "memory");
                __builtin_amdgcn_sched_barrier(0);

                __builtin_amdgcn_s_setprio(1);
#pragma unroll
                for (int ks = 0; ks < 2; ++ks) {
                    bf16x8 pa = *(const bf16x8*)(ps + lq * 128 + ((ks * 64 + g * 16) ^ psw));
#pragma unroll
                    for (int nb = 0; nb < 8; ++nb) {
                        int d = nb * 16 + lq;
                        bf16x8 vf = *(const bf16x8*)((const char*)Vs + d * 128 + ((ks * 64 + g * 16) ^ ((d & 7) << 4)));
                        acc[nb] = __builtin_amdgcn_mfma_f32_16x16x32_bf16(pa, vf, acc[nb], 0, 0, 0);
                    }
                }
                __builtin_amdgcn_s_setprio(0);
                __builtin_amdgcn_sched_barrier(0);
            }
        }
        __builtin_amdgcn_sched_barrier(0);
    }

    l0 += __shfl_xor(l0, 16); l0 += __shfl_xor(l0, 32);
    l1 += __shfl_xor(l1, 16); l1 += __shfl_xor(l1, 32);
    float rl0 = 1.f / l0, rl1 = 1.f / l1;
#pragma unroll
    for (int r = 0; r < 4; ++r) {
        float rr0 = __shfl(rl0, g * 4 + r);
        float rr1 = __shfl(rl1, g * 4 + r);
        size_t row0 = (size_t)(b * S) + wqmin + g * 4 + r;
        __bf16* orow0 = outb + row0 * 4096 + h * D;
        __bf16* orow1 = orow0 + (size_t)16 * 4096;
#pragma unroll
        for (int nb = 0; nb < 8; ++nb) {
            orow0[nb * 16 + lq] = (__bf16)(acc0[nb][r] * rr0);
            orow1[nb * 16 + lq] = (__bf16)(acc1[nb][r] * rr1);
        }
    }
}

// ---------------- launch ----------------
extern "C" void kernel_launch(void* const* d_in, const int* in_sizes, int n_in,
                              void* d_out, int out_size, void* d_ws, size_t ws_size,
                              hipStream_t stream) {
    (void)in_sizes; (void)n_in; (void)out_size; (void)ws_size;
    const float* q       = (const float*)d_in[0];
    const float* w_qkv   = (const float*)d_in[1];
    const float* w_dense = (const float*)d_in[2];
    float* out = (float*)d_out;
    char* ws = (char*)d_ws;

    __bf16* qbf      = (__bf16*)(ws);
    __bf16* wqkvbf   = (__bf16*)(ws + 33554432ULL);
    __bf16* wdensebf = (__bf16*)(ws + 83886080ULL);
    __bf16* qkvbf    = (__bf16*)(ws + 117440512ULL);
    __bf16* vtbf     = (__bf16*)(ws + 167772160ULL);
    __bf16* attnbf   = (__bf16*)(ws + 176160768ULL);

    cast_all<<<28672, 256, 0, stream>>>(q, w_qkv, w_dense, qbf, wqkvbf, wdensebf);

    gemm_bt<1><<<dim3(48, 32), 256, 0, stream>>>(qbf, wqkvbf, (void*)qkvbf, 4096, 6144, 4096);
    transpose_v<<<dim3(32, 32), 256, 0, stream>>>(qkvbf, vtbf);
    attn_kernel<<<1024, 256, 0, stream>>>(qkvbf, vtbf, attnbf);
    gemm256<0><<<dim3(16, 16), 512, 0, stream>>>(attnbf, wdensebf, (void*)out, 4096, 4096, 4096);
}